// Round 7
// baseline (130.503 us; speedup 1.0000x reference)
//
#include <hip/hip_runtime.h>
#include <math.h>

typedef __bf16 bf16;
typedef __bf16 bf16x8 __attribute__((ext_vector_type(8)));
typedef __bf16 bf16x4 __attribute__((ext_vector_type(4)));
typedef float  f32x4  __attribute__((ext_vector_type(4)));

constexpr int BATCH = 4096;
constexpr int HID   = 512;
constexpr int NSTEP = 16;
constexpr int SLICE = BATCH * HID;   // elements per [B,H] plane
constexpr int S4    = SLICE / 4;     // float4s per plane

__device__ __forceinline__ float sigmoidf_(float x) {
    return 1.0f / (1.0f + __expf(-x));
}
__device__ __forceinline__ float tanh_fast(float x) {
    x = fminf(fmaxf(x, -15.0f), 15.0f);
    float e = __expf(2.0f * x);
    return (e - 1.0f) / (e + 1.0f);
}

__device__ __forceinline__ void gload_lds16(const void* g, void* l) {
    __builtin_amdgcn_global_load_lds((const __attribute__((address_space(1))) void*)g,
                                     (__attribute__((address_space(3))) void*)l,
                                     16, 0, 0);
}

// ---------------------------------------------------------------------------
// Fused prep: blocks [0,6144) convert sample/hidden/mem_para f32->bf16;
// blocks [6144,8704) transpose-convert the five weight matrices to B^T bf16.
__global__ __launch_bounds__(256)
void prep_all(const float* __restrict__ sample,
              const float* __restrict__ hidden,
              const float* __restrict__ mem_para,
              const float* __restrict__ Wu, const float* __restrict__ Wr,
              const float* __restrict__ Wm, const float* __restrict__ Wh,
              const float* __restrict__ Wo,
              bf16* __restrict__ Sb, bf16* __restrict__ Hb, bf16* __restrict__ Mb,
              bf16* __restrict__ Wall_t, bf16* __restrict__ Wh_t,
              bf16* __restrict__ Wo_t) {
    __shared__ float tile[32][33];
    const int bid = blockIdx.x;
    if (bid < 6144) {
        const int seg = bid >> 11;              // 0,1,2
        const int i = (bid & 2047) * 256 + threadIdx.x; // float4 index < S4
        const float* in = (seg == 0) ? sample : (seg == 1) ? hidden : mem_para;
        bf16* out = (seg == 0) ? Sb : (seg == 1) ? Hb : Mb;
        float4 v = ((const float4*)in)[i];
        bf16x4 o = {(bf16)v.x, (bf16)v.y, (bf16)v.z, (bf16)v.w};
        ((bf16x4*)out)[i] = o;
        return;
    }
    const int t = bid - 6144;                   // 0..2559: 32x32 transpose tiles
    const float* in; bf16* out; int stride, row_off, t2;
    if (t < 512)        { in = Wu; out = Wall_t; stride = 1536; row_off = 0;    t2 = t; }
    else if (t < 1024)  { in = Wr; out = Wall_t; stride = 1536; row_off = 512;  t2 = t - 512; }
    else if (t < 1792)  { in = Wm; out = Wall_t; stride = 1536; row_off = 1024; t2 = t - 1024; }
    else if (t < 2304)  { in = Wh; out = Wh_t;   stride = 1024; row_off = 0;    t2 = t - 1792; }
    else                { in = Wo; out = Wo_t;   stride = 512;  row_off = 0;    t2 = t - 2304; }
    const int r0 = (t2 >> 4) * 32, c0 = (t2 & 15) * 32;
    const int tr = threadIdx.x >> 5;   // 0..7
    const int tc = threadIdx.x & 31;   // 0..31
#pragma unroll
    for (int i = 0; i < 4; ++i)
        tile[tr + i * 8][tc] = in[(size_t)(r0 + tr + i * 8) * 512 + c0 + tc];
    __syncthreads();
#pragma unroll
    for (int i = 0; i < 4; ++i) {
        const int c = tr + i * 8;
        out[(size_t)(row_off + c0 + c) * stride + r0 + tc] = (bf16)tile[tc][c];
    }
}

// ---------------------------------------------------------------------------
// K2: URM GEMM (blocks [0,768)) UNION shifted copy (blocks [768, 768+1920)).
// GEMM: tile BM=128 BN=64 BK=64, 4 waves 2x2, wave 64x32; per-block K
// (U/R cols: 16 K-tiles, M cols: 24).
// Copy: out_upd[0..15) = hiddens[1..16), nontemporal float4 streaming
// (240 MB hides under the GEMM's MFMA; nt keeps it out of L2/L3).
__global__ __launch_bounds__(256)
void gemm_urm_copy(const bf16* __restrict__ Sb,
                   const bf16* __restrict__ Hb,
                   const bf16* __restrict__ Mb,
                   const bf16* __restrict__ Wall_t,
                   const float* __restrict__ bu,
                   const float* __restrict__ br,
                   const float* __restrict__ bm,
                   bf16* __restrict__ UGb,
                   bf16* __restrict__ RHb,
                   float* __restrict__ out_mg,
                   const float* __restrict__ hiddens,
                   float* __restrict__ out_upd) {
    __shared__ bf16 As[128 * 64];   // 16KB
    __shared__ bf16 Bs[64 * 64];    // 8KB

    const int bid = blockIdx.x;
    const int tid = threadIdx.x;

    if (bid >= 768) {
        // ---- streaming copy: 1920 blocks x 256 thr x 16 float4
        const int base = (bid - 768) * 4096 + tid;
        const f32x4* src = ((const f32x4*)hiddens) + S4;   // slice 1 start
        f32x4* dst = (f32x4*)out_upd;
#pragma unroll
        for (int u = 0; u < 16; ++u) {
            const int f = base + u * 256;
            f32x4 v = __builtin_nontemporal_load(src + f);
            __builtin_nontemporal_store(v, dst + f);
        }
        return;
    }

    const int wid  = tid >> 6;
    const int lane = tid & 63;
    const int wr = wid >> 1, wc = wid & 1;
    const int brow = (bid & 31) * 128;
    const int bcol = (bid >> 5) * 64;

    const bf16* segs[3] = {Sb, Hb, Mb};
    const int nkt = (bcol >= 1024) ? 24 : 16;

    const int s_row  = tid >> 3;
    const int s_chnk = tid & 7;

    f32x4 acc[4][2] = {};

    for (int t = 0; t < nkt; ++t) {
        const int k0 = t * 64;
        const bf16* Aseg = segs[k0 >> 9];
        const int kloc = k0 & 511;

#pragma unroll
        for (int c = 0; c < 4; ++c) {
            const int row = c * 32 + s_row;
            const int sc  = s_chnk ^ (row & 7);
            gload_lds16(Aseg + (size_t)(brow + row) * 512 + kloc + sc * 8,
                        As + (size_t)(c * 256 + (wid << 6)) * 8);
        }
#pragma unroll
        for (int c = 0; c < 2; ++c) {
            const int row = c * 32 + s_row;
            const int sc  = s_chnk ^ (row & 7);
            gload_lds16(Wall_t + (size_t)(bcol + row) * 1536 + k0 + sc * 8,
                        Bs + (size_t)(c * 256 + (wid << 6)) * 8);
        }
        __syncthreads();

#pragma unroll
        for (int ks = 0; ks < 2; ++ks) {
            const int kb = ks * 64 + ((lane >> 4) << 4);
            bf16x8 bfrag[2];
#pragma unroll
            for (int ni = 0; ni < 2; ++ni) {
                const int n = wc * 32 + ni * 16 + (lane & 15);
                bfrag[ni] = *(const bf16x8*)((const char*)Bs +
                                             n * 128 + (kb ^ ((n & 7) << 4)));
            }
#pragma unroll
            for (int mi = 0; mi < 4; ++mi) {
                const int m = wr * 64 + mi * 16 + (lane & 15);
                const bf16x8 afrag = *(const bf16x8*)((const char*)As +
                                                      m * 128 + (kb ^ ((m & 7) << 4)));
#pragma unroll
                for (int ni = 0; ni < 2; ++ni)
                    acc[mi][ni] = __builtin_amdgcn_mfma_f32_16x16x32_bf16(
                        afrag, bfrag[ni], acc[mi][ni], 0, 0, 0);
            }
        }
        __syncthreads();
    }

    const int lr4 = (lane >> 4) * 4;
    const int lc  = lane & 15;
#pragma unroll
    for (int mi = 0; mi < 4; ++mi) {
#pragma unroll
        for (int ni = 0; ni < 2; ++ni) {
            const int col = bcol + wc * 32 + ni * 16 + lc;
            const f32x4 a = acc[mi][ni];
#pragma unroll
            for (int r = 0; r < 4; ++r) {
                const int row = brow + wr * 64 + mi * 16 + lr4 + r;
                const float x = a[r];
                if (col < 512) {
                    UGb[(size_t)row * 512 + col] = (bf16)sigmoidf_(x + bu[col]);
                } else if (col < 1024) {
                    const int c2 = col - 512;
                    const float v = sigmoidf_(x + br[c2]) *
                                    (float)Hb[(size_t)row * 512 + c2];
                    RHb[(size_t)row * 512 + c2] = (bf16)v;
                } else {
                    const int c3 = col - 1024;
                    out_mg[(size_t)row * 512 + c3] = 0.5f * sigmoidf_(x + bm[c3]);
                }
            }
        }
    }
}

// ---------------------------------------------------------------------------
// K3: Wh GEMM (blocks [0,256)) UNION memory-filter weighted sum
// (blocks [256, 256+2048)). Sum: filt[b,h] = sum_i hiddens[15-i]*cumprod_i,
// nontemporal reads of hiddens (128 MB streams under Wh's MFMA).
__global__ __launch_bounds__(256)
void gemm_wh_sum(const bf16* __restrict__ Sb,
                 const bf16* __restrict__ RHb,
                 const bf16* __restrict__ Wh_t,
                 const float* __restrict__ bh,
                 bf16* __restrict__ HTb,
                 const float* __restrict__ hiddens,
                 const float* __restrict__ mg,
                 float* __restrict__ filt) {
    __shared__ bf16 As[128 * 64];   // 16KB
    __shared__ bf16 Bs[64 * 64];    // 8KB

    const int bid = blockIdx.x;
    const int tid = threadIdx.x;

    if (bid >= 256) {
        // ---- filter weighted sum: 2048 blocks x 256 thr, one f32x4 each
        const int idx = (bid - 256) * 256 + tid;
        const f32x4 d = ((const f32x4*)mg)[idx];
        f32x4 c = {1.f, 1.f, 1.f, 1.f};
        f32x4 a = {0.f, 0.f, 0.f, 0.f};
#pragma unroll
        for (int i = 0; i < NSTEP; ++i) {
            const int j = NSTEP - 1 - i;
            const f32x4 v = __builtin_nontemporal_load(
                ((const f32x4*)hiddens) + (size_t)j * S4 + idx);
            const float fi = (float)i;
            const float inv = 1.0f / (float)(i + 1);
            c *= (fi - d) * inv;
            a += v * c;
        }
        __builtin_nontemporal_store(a, ((f32x4*)filt) + idx);
        return;
    }

    const int wid  = tid >> 6;
    const int lane = tid & 63;
    const int wr = wid >> 1, wc = wid & 1;
    const int brow = (bid & 31) * 128;
    const int bcol = (bid >> 5) * 64;

    const bf16* segs[2] = {Sb, RHb};

    const int s_row  = tid >> 3;
    const int s_chnk = tid & 7;

    f32x4 acc[4][2] = {};

    for (int t = 0; t < 16; ++t) {
        const int k0 = t * 64;
        const bf16* Aseg = segs[k0 >> 9];
        const int kloc = k0 & 511;

#pragma unroll
        for (int c = 0; c < 4; ++c) {
            const int row = c * 32 + s_row;
            const int sc  = s_chnk ^ (row & 7);
            gload_lds16(Aseg + (size_t)(brow + row) * 512 + kloc + sc * 8,
                        As + (size_t)(c * 256 + (wid << 6)) * 8);
        }
#pragma unroll
        for (int c = 0; c < 2; ++c) {
            const int row = c * 32 + s_row;
            const int sc  = s_chnk ^ (row & 7);
            gload_lds16(Wh_t + (size_t)(bcol + row) * 1024 + k0 + sc * 8,
                        Bs + (size_t)(c * 256 + (wid << 6)) * 8);
        }
        __syncthreads();

#pragma unroll
        for (int ks = 0; ks < 2; ++ks) {
            const int kb = ks * 64 + ((lane >> 4) << 4);
            bf16x8 bfrag[2];
#pragma unroll
            for (int ni = 0; ni < 2; ++ni) {
                const int n = wc * 32 + ni * 16 + (lane & 15);
                bfrag[ni] = *(const bf16x8*)((const char*)Bs +
                                             n * 128 + (kb ^ ((n & 7) << 4)));
            }
#pragma unroll
            for (int mi = 0; mi < 4; ++mi) {
                const int m = wr * 64 + mi * 16 + (lane & 15);
                const bf16x8 afrag = *(const bf16x8*)((const char*)As +
                                                      m * 128 + (kb ^ ((m & 7) << 4)));
#pragma unroll
                for (int ni = 0; ni < 2; ++ni)
                    acc[mi][ni] = __builtin_amdgcn_mfma_f32_16x16x32_bf16(
                        afrag, bfrag[ni], acc[mi][ni], 0, 0, 0);
            }
        }
        __syncthreads();
    }

    const int lr4 = (lane >> 4) * 4;
    const int lc  = lane & 15;
#pragma unroll
    for (int mi = 0; mi < 4; ++mi) {
#pragma unroll
        for (int ni = 0; ni < 2; ++ni) {
            const int col = bcol + wc * 32 + ni * 16 + lc;
            const f32x4 a = acc[mi][ni];
#pragma unroll
            for (int r = 0; r < 4; ++r) {
                const int row = brow + wr * 64 + mi * 16 + lr4 + r;
                HTb[(size_t)row * 512 + col] = (bf16)tanh_fast(a[r] + bh[col]);
            }
        }
    }
}

// ---------------------------------------------------------------------------
// K4: combine hn = ug*ht - filt -> out_upd[15] (f32) + HNb (bf16)
__global__ __launch_bounds__(256)
void combine(const float* __restrict__ filt,
             const bf16* __restrict__ ugb,
             const bf16* __restrict__ htb,
             float* __restrict__ out_upd,
             bf16* __restrict__ hnb) {
    const int idx = blockIdx.x * 256 + threadIdx.x;
    const f32x4 a = ((const f32x4*)filt)[idx];
    const bf16x4 u = ((const bf16x4*)ugb)[idx];
    const bf16x4 t = ((const bf16x4*)htb)[idx];
    f32x4 hn;
#pragma unroll
    for (int e = 0; e < 4; ++e)
        hn[e] = fmaf((float)u[e], (float)t[e], -a[e]);
    ((f32x4*)out_upd)[(size_t)(NSTEP - 1) * S4 + idx] = hn;
    bf16x4 hb = {(bf16)hn[0], (bf16)hn[1], (bf16)hn[2], (bf16)hn[3]};
    ((bf16x4*)hnb)[idx] = hb;
}

// ---------------------------------------------------------------------------
// K5: output GEMM (N=512, K=512): out = HNb @ Wo + bo (f32)
__global__ __launch_bounds__(256)
void gemm_out(const bf16* __restrict__ HNb,
              const bf16* __restrict__ Wo_t,
              const float* __restrict__ bo,
              float* __restrict__ outp) {
    __shared__ bf16 As[128 * 64];
    __shared__ bf16 Bs[64 * 64];

    const int tid  = threadIdx.x;
    const int wid  = tid >> 6;
    const int lane = tid & 63;
    const int wr = wid >> 1, wc = wid & 1;
    const int brow = blockIdx.x * 128;
    const int bcol = blockIdx.y * 64;

    const int s_row  = tid >> 3;
    const int s_chnk = tid & 7;

    f32x4 acc[4][2] = {};

    for (int t = 0; t < 8; ++t) {
        const int k0 = t * 64;

#pragma unroll
        for (int c = 0; c < 4; ++c) {
            const int row = c * 32 + s_row;
            const int sc  = s_chnk ^ (row & 7);
            gload_lds16(HNb + (size_t)(brow + row) * 512 + k0 + sc * 8,
                        As + (size_t)(c * 256 + (wid << 6)) * 8);
        }
#pragma unroll
        for (int c = 0; c < 2; ++c) {
            const int row = c * 32 + s_row;
            const int sc  = s_chnk ^ (row & 7);
            gload_lds16(Wo_t + (size_t)(bcol + row) * 512 + k0 + sc * 8,
                        Bs + (size_t)(c * 256 + (wid << 6)) * 8);
        }
        __syncthreads();

#pragma unroll
        for (int ks = 0; ks < 2; ++ks) {
            const int kb = ks * 64 + ((lane >> 4) << 4);
            bf16x8 bfrag[2];
#pragma unroll
            for (int ni = 0; ni < 2; ++ni) {
                const int n = wc * 32 + ni * 16 + (lane & 15);
                bfrag[ni] = *(const bf16x8*)((const char*)Bs +
                                             n * 128 + (kb ^ ((n & 7) << 4)));
            }
#pragma unroll
            for (int mi = 0; mi < 4; ++mi) {
                const int m = wr * 64 + mi * 16 + (lane & 15);
                const bf16x8 afrag = *(const bf16x8*)((const char*)As +
                                                      m * 128 + (kb ^ ((m & 7) << 4)));
#pragma unroll
                for (int ni = 0; ni < 2; ++ni)
                    acc[mi][ni] = __builtin_amdgcn_mfma_f32_16x16x32_bf16(
                        afrag, bfrag[ni], acc[mi][ni], 0, 0, 0);
            }
        }
        __syncthreads();
    }

    const int lr4 = (lane >> 4) * 4;
    const int lc  = lane & 15;
#pragma unroll
    for (int mi = 0; mi < 4; ++mi) {
#pragma unroll
        for (int ni = 0; ni < 2; ++ni) {
            const int col = bcol + wc * 32 + ni * 16 + lc;
            const f32x4 a = acc[mi][ni];
#pragma unroll
            for (int r = 0; r < 4; ++r) {
                const int row = brow + wr * 64 + mi * 16 + lr4 + r;
                outp[(size_t)row * 512 + col] = a[r] + bo[col];
            }
        }
    }
}

// ---------------------------------------------------------------------------
extern "C" void kernel_launch(void* const* d_in, const int* in_sizes, int n_in,
                              void* d_out, int out_size, void* d_ws, size_t ws_size,
                              hipStream_t stream) {
    const float* sample   = (const float*)d_in[0];
    const float* hiddens  = (const float*)d_in[1];
    const float* mem_para = (const float*)d_in[2];
    const float* Wu = (const float*)d_in[3];
    const float* bu = (const float*)d_in[4];
    const float* Wr = (const float*)d_in[5];
    const float* br = (const float*)d_in[6];
    const float* Wm = (const float*)d_in[7];
    const float* bm = (const float*)d_in[8];
    const float* Wh = (const float*)d_in[9];
    const float* bh = (const float*)d_in[10];
    const float* Wo = (const float*)d_in[11];
    const float* bo = (const float*)d_in[12];

    float* out        = (float*)d_out;
    float* out_output = out;                                  // [B,512]
    float* out_upd    = out + SLICE;                          // [16,B,512]
    float* out_mg     = out + SLICE + (size_t)NSTEP * SLICE;  // [B,512]

    const float* hidden = hiddens + (size_t)(NSTEP - 1) * SLICE;

    // workspace layout; 4MB-aligned chunks
    char* ws = (char*)d_ws;
    bf16* Sb    = (bf16*)(ws);                          // sample bf16
    bf16* Hb    = (bf16*)(ws + (((size_t) 4) << 20));   // hidden bf16
    bf16* Mb    = (bf16*)(ws + (((size_t) 8) << 20));   // mem_para bf16
    bf16* RHb   = (bf16*)(ws + (((size_t)12) << 20));   // reset_gate*hidden
    bf16* HNb   = (bf16*)(ws + (((size_t)16) << 20));   // hidden_now
    bf16* UGb   = (bf16*)(ws + (((size_t)20) << 20));   // update_gate
    bf16* HTb   = (bf16*)(ws + (((size_t)24) << 20));   // h_tilde
    bf16* Wall_t = (bf16*)(ws + (((size_t)28) << 20));  // [1536][1536] (4.5MB)
    bf16* Wh_t  = (bf16*)(ws + (((size_t)33) << 20));   // [512][1024]
    bf16* Wo_t  = (bf16*)(ws + (((size_t)35) << 20));   // [512][512]
    float* filt = (float*)(ws + (((size_t)40) << 20));  // [B,512] f32 (8MB)

    dim3 blk(256);

    // 1. fused prep: converts + all weight transposes
    prep_all<<<8704, blk, 0, stream>>>(sample, hidden, mem_para,
                                       Wu, Wr, Wm, Wh, Wo,
                                       Sb, Hb, Mb, Wall_t, Wh_t, Wo_t);
    // 2. URM GEMM (768) + shifted copy (1920)
    gemm_urm_copy<<<768 + 1920, blk, 0, stream>>>(
        Sb, Hb, Mb, Wall_t, bu, br, bm, UGb, RHb, out_mg, hiddens, out_upd);
    // 3. Wh GEMM (256) + filter weighted sum (2048)
    gemm_wh_sum<<<256 + 2048, blk, 0, stream>>>(
        Sb, RHb, Wh_t, bh, HTb, hiddens, out_mg, filt);
    // 4. combine -> out_upd[15] + HNb
    combine<<<S4 / 256, blk, 0, stream>>>(filt, UGb, HTb, out_upd, HNb);
    // 5. output GEMM
    gemm_out<<<dim3(32, 8), blk, 0, stream>>>(HNb, Wo_t, bo, out_output);
}

// Round 8
// 107.812 us; speedup vs baseline: 1.2105x; 1.2105x over previous
//
#include <hip/hip_runtime.h>
#include <math.h>

typedef __bf16 bf16;
typedef __bf16 bf16x8 __attribute__((ext_vector_type(8)));
typedef __bf16 bf16x4 __attribute__((ext_vector_type(4)));
typedef float  f32x4  __attribute__((ext_vector_type(4)));

constexpr int BATCH = 4096;
constexpr int HID   = 512;
constexpr int NSTEP = 16;
constexpr int SLICE = BATCH * HID;   // elements per [B,H] plane
constexpr int S4    = SLICE / 4;     // float4s per plane

__device__ __forceinline__ float sigmoidf_(float x) {
    return 1.0f / (1.0f + __expf(-x));
}
__device__ __forceinline__ float tanh_fast(float x) {
    x = fminf(fmaxf(x, -15.0f), 15.0f);
    float e = __expf(2.0f * x);
    return (e - 1.0f) / (e + 1.0f);
}

__device__ __forceinline__ void gload_lds16(const void* g, void* l) {
    __builtin_amdgcn_global_load_lds((const __attribute__((address_space(1))) void*)g,
                                     (__attribute__((address_space(3))) void*)l,
                                     16, 0, 0);
}

// ---------------------------------------------------------------------------
// Fused prep: blocks [0,6144) convert sample/hidden/mem_para f32->bf16;
// blocks [6144,8704) transpose-convert the five weight matrices to B^T bf16.
__global__ __launch_bounds__(256)
void prep_all(const float* __restrict__ sample,
              const float* __restrict__ hidden,
              const float* __restrict__ mem_para,
              const float* __restrict__ Wu, const float* __restrict__ Wr,
              const float* __restrict__ Wm, const float* __restrict__ Wh,
              const float* __restrict__ Wo,
              bf16* __restrict__ Sb, bf16* __restrict__ Hb, bf16* __restrict__ Mb,
              bf16* __restrict__ Wall_t, bf16* __restrict__ Wh_t,
              bf16* __restrict__ Wo_t) {
    __shared__ float tile[32][33];
    const int bid = blockIdx.x;
    if (bid < 6144) {
        const int seg = bid >> 11;              // 0,1,2
        const int i = (bid & 2047) * 256 + threadIdx.x; // float4 index < S4
        const float* in = (seg == 0) ? sample : (seg == 1) ? hidden : mem_para;
        bf16* out = (seg == 0) ? Sb : (seg == 1) ? Hb : Mb;
        float4 v = ((const float4*)in)[i];
        bf16x4 o = {(bf16)v.x, (bf16)v.y, (bf16)v.z, (bf16)v.w};
        ((bf16x4*)out)[i] = o;
        return;
    }
    const int t = bid - 6144;                   // 0..2559: 32x32 transpose tiles
    const float* in; bf16* out; int stride, row_off, t2;
    if (t < 512)        { in = Wu; out = Wall_t; stride = 1536; row_off = 0;    t2 = t; }
    else if (t < 1024)  { in = Wr; out = Wall_t; stride = 1536; row_off = 512;  t2 = t - 512; }
    else if (t < 1792)  { in = Wm; out = Wall_t; stride = 1536; row_off = 1024; t2 = t - 1024; }
    else if (t < 2304)  { in = Wh; out = Wh_t;   stride = 1024; row_off = 0;    t2 = t - 1792; }
    else                { in = Wo; out = Wo_t;   stride = 512;  row_off = 0;    t2 = t - 2304; }
    const int r0 = (t2 >> 4) * 32, c0 = (t2 & 15) * 32;
    const int tr = threadIdx.x >> 5;   // 0..7
    const int tc = threadIdx.x & 31;   // 0..31
#pragma unroll
    for (int i = 0; i < 4; ++i)
        tile[tr + i * 8][tc] = in[(size_t)(r0 + tr + i * 8) * 512 + c0 + tc];
    __syncthreads();
#pragma unroll
    for (int i = 0; i < 4; ++i) {
        const int c = tr + i * 8;
        out[(size_t)(row_off + c0 + c) * stride + r0 + tc] = (bf16)tile[tc][c];
    }
}

// ---------------------------------------------------------------------------
// K2: URM GEMM, tile BM=128 BN=64 BK=64, 768 blocks, XCD-locality swizzle:
// XCD k (= bid%8) owns row-strips [4k,4k+4) and walks all 24 col-strips --
// per-XCD L2 working set = 4 A-panels (<=1.5MB, pinned) + active B-panels.
// Per-block K: U/R cols (col<16): 16 K-tiles; M cols: 24.
__global__ __launch_bounds__(256)
void gemm_urm(const bf16* __restrict__ Sb,
              const bf16* __restrict__ Hb,
              const bf16* __restrict__ Mb,
              const bf16* __restrict__ Wall_t,
              const float* __restrict__ bu,
              const float* __restrict__ br,
              const float* __restrict__ bm,
              bf16* __restrict__ UGb,
              bf16* __restrict__ RHb,
              float* __restrict__ out_mg) {
    __shared__ bf16 As[128 * 64];   // 16KB
    __shared__ bf16 Bs[64 * 64];    // 8KB

    const int bid = blockIdx.x;
    const int tid = threadIdx.x;

    // XCD swizzle: k8 = XCD, s walks col-major within the XCD's 4 row-strips
    const int k8  = bid & 7;
    const int s   = bid >> 3;          // 0..95
    const int colb = s >> 2;           // 0..23
    const int rowb = (k8 << 2) + (s & 3);  // 0..31
    const int brow = rowb * 128;
    const int bcol = colb * 64;

    const int wid  = tid >> 6;
    const int lane = tid & 63;
    const int wr = wid >> 1, wc = wid & 1;

    const bf16* segs[3] = {Sb, Hb, Mb};
    const int nkt = (colb >= 16) ? 24 : 16;

    const int s_row  = tid >> 3;
    const int s_chnk = tid & 7;

    f32x4 acc[4][2] = {};

    for (int t = 0; t < nkt; ++t) {
        const int k0 = t * 64;
        const bf16* Aseg = segs[k0 >> 9];
        const int kloc = k0 & 511;

#pragma unroll
        for (int c = 0; c < 4; ++c) {
            const int row = c * 32 + s_row;
            const int sc  = s_chnk ^ (row & 7);
            gload_lds16(Aseg + (size_t)(brow + row) * 512 + kloc + sc * 8,
                        As + (size_t)(c * 256 + (wid << 6)) * 8);
        }
#pragma unroll
        for (int c = 0; c < 2; ++c) {
            const int row = c * 32 + s_row;
            const int sc  = s_chnk ^ (row & 7);
            gload_lds16(Wall_t + (size_t)(bcol + row) * 1536 + k0 + sc * 8,
                        Bs + (size_t)(c * 256 + (wid << 6)) * 8);
        }
        __syncthreads();

#pragma unroll
        for (int ks = 0; ks < 2; ++ks) {
            const int kb = ks * 64 + ((lane >> 4) << 4);
            bf16x8 bfrag[2];
#pragma unroll
            for (int ni = 0; ni < 2; ++ni) {
                const int n = wc * 32 + ni * 16 + (lane & 15);
                bfrag[ni] = *(const bf16x8*)((const char*)Bs +
                                             n * 128 + (kb ^ ((n & 7) << 4)));
            }
#pragma unroll
            for (int mi = 0; mi < 4; ++mi) {
                const int m = wr * 64 + mi * 16 + (lane & 15);
                const bf16x8 afrag = *(const bf16x8*)((const char*)As +
                                                      m * 128 + (kb ^ ((m & 7) << 4)));
#pragma unroll
                for (int ni = 0; ni < 2; ++ni)
                    acc[mi][ni] = __builtin_amdgcn_mfma_f32_16x16x32_bf16(
                        afrag, bfrag[ni], acc[mi][ni], 0, 0, 0);
            }
        }
        __syncthreads();
    }

    const int lr4 = (lane >> 4) * 4;
    const int lc  = lane & 15;
#pragma unroll
    for (int mi = 0; mi < 4; ++mi) {
#pragma unroll
        for (int ni = 0; ni < 2; ++ni) {
            const int col = bcol + wc * 32 + ni * 16 + lc;
            const f32x4 a = acc[mi][ni];
#pragma unroll
            for (int r = 0; r < 4; ++r) {
                const int row = brow + wr * 64 + mi * 16 + lr4 + r;
                const float x = a[r];
                if (col < 512) {
                    UGb[(size_t)row * 512 + col] = (bf16)sigmoidf_(x + bu[col]);
                } else if (col < 1024) {
                    const int c2 = col - 512;
                    const float v = sigmoidf_(x + br[c2]) *
                                    (float)Hb[(size_t)row * 512 + c2];
                    RHb[(size_t)row * 512 + c2] = (bf16)v;
                } else {
                    const int c3 = col - 1024;
                    out_mg[(size_t)row * 512 + c3] = 0.5f * sigmoidf_(x + bm[c3]);
                }
            }
        }
    }
}

// ---------------------------------------------------------------------------
// K3: Wh GEMM (blocks [0,256), XCD-swizzled) UNION filter stream
// (blocks [256,2304)): per f32x4 lane-slot, read hiddens[j] once, write the
// shifted copy (nt stores -- no L2 pollution) and accumulate the
// signed-binomial weighted sum -> filt (f32).
__global__ __launch_bounds__(256)
void gemm_wh_filter(const bf16* __restrict__ Sb,
                    const bf16* __restrict__ RHb,
                    const bf16* __restrict__ Wh_t,
                    const float* __restrict__ bh,
                    bf16* __restrict__ HTb,
                    const float* __restrict__ hiddens,
                    const float* __restrict__ mg,
                    float* __restrict__ out_upd,
                    float* __restrict__ filt) {
    __shared__ bf16 As[128 * 64];   // 16KB
    __shared__ bf16 Bs[64 * 64];    // 8KB

    const int bid = blockIdx.x;
    const int tid = threadIdx.x;

    if (bid >= 256) {
        // ---- filter: copy + weighted sum, 2048 blocks x 256 thr x 1 f32x4
        const int idx = (bid - 256) * 256 + tid;
        const f32x4* h4 = (const f32x4*)hiddens;
        f32x4* o4 = (f32x4*)out_upd;
        const f32x4 d = ((const f32x4*)mg)[idx];
        f32x4 c = {1.f, 1.f, 1.f, 1.f};
        f32x4 a = {0.f, 0.f, 0.f, 0.f};
#pragma unroll
        for (int i = 0; i < NSTEP; ++i) {
            const int j = NSTEP - 1 - i;
            const f32x4 v = h4[(size_t)j * S4 + idx];
            const float fi = (float)i;
            const float inv = 1.0f / (float)(i + 1);
            c *= (fi - d) * inv;
            a += v * c;
            if (j >= 1)
                __builtin_nontemporal_store(v, o4 + (size_t)(j - 1) * S4 + idx);
        }
        ((f32x4*)filt)[idx] = a;
        return;
    }

    // ---- Wh GEMM: 256 blocks = 32 row-strips x 8 col-strips, XCD swizzle
    const int k8  = bid & 7;
    const int s   = bid >> 3;          // 0..31
    const int colb = s >> 2;           // 0..7
    const int rowb = (k8 << 2) + (s & 3);
    const int brow = rowb * 128;
    const int bcol = colb * 64;

    const int wid  = tid >> 6;
    const int lane = tid & 63;
    const int wr = wid >> 1, wc = wid & 1;

    const bf16* segs[2] = {Sb, RHb};

    const int s_row  = tid >> 3;
    const int s_chnk = tid & 7;

    f32x4 acc[4][2] = {};

    for (int t = 0; t < 16; ++t) {
        const int k0 = t * 64;
        const bf16* Aseg = segs[k0 >> 9];
        const int kloc = k0 & 511;

#pragma unroll
        for (int c = 0; c < 4; ++c) {
            const int row = c * 32 + s_row;
            const int sc  = s_chnk ^ (row & 7);
            gload_lds16(Aseg + (size_t)(brow + row) * 512 + kloc + sc * 8,
                        As + (size_t)(c * 256 + (wid << 6)) * 8);
        }
#pragma unroll
        for (int c = 0; c < 2; ++c) {
            const int row = c * 32 + s_row;
            const int sc  = s_chnk ^ (row & 7);
            gload_lds16(Wh_t + (size_t)(bcol + row) * 1024 + k0 + sc * 8,
                        Bs + (size_t)(c * 256 + (wid << 6)) * 8);
        }
        __syncthreads();

#pragma unroll
        for (int ks = 0; ks < 2; ++ks) {
            const int kb = ks * 64 + ((lane >> 4) << 4);
            bf16x8 bfrag[2];
#pragma unroll
            for (int ni = 0; ni < 2; ++ni) {
                const int n = wc * 32 + ni * 16 + (lane & 15);
                bfrag[ni] = *(const bf16x8*)((const char*)Bs +
                                             n * 128 + (kb ^ ((n & 7) << 4)));
            }
#pragma unroll
            for (int mi = 0; mi < 4; ++mi) {
                const int m = wr * 64 + mi * 16 + (lane & 15);
                const bf16x8 afrag = *(const bf16x8*)((const char*)As +
                                                      m * 128 + (kb ^ ((m & 7) << 4)));
#pragma unroll
                for (int ni = 0; ni < 2; ++ni)
                    acc[mi][ni] = __builtin_amdgcn_mfma_f32_16x16x32_bf16(
                        afrag, bfrag[ni], acc[mi][ni], 0, 0, 0);
            }
        }
        __syncthreads();
    }

    const int lr4 = (lane >> 4) * 4;
    const int lc  = lane & 15;
#pragma unroll
    for (int mi = 0; mi < 4; ++mi) {
#pragma unroll
        for (int ni = 0; ni < 2; ++ni) {
            const int col = bcol + wc * 32 + ni * 16 + lc;
            const f32x4 a = acc[mi][ni];
#pragma unroll
            for (int r = 0; r < 4; ++r) {
                const int row = brow + wr * 64 + mi * 16 + lr4 + r;
                HTb[(size_t)row * 512 + col] = (bf16)tanh_fast(a[r] + bh[col]);
            }
        }
    }
}

// ---------------------------------------------------------------------------
// K4: combine hn = ug*ht - filt -> out_upd[15] (f32) + HNb (bf16)
__global__ __launch_bounds__(256)
void combine(const float* __restrict__ filt,
             const bf16* __restrict__ ugb,
             const bf16* __restrict__ htb,
             float* __restrict__ out_upd,
             bf16* __restrict__ hnb) {
    const int idx = blockIdx.x * 256 + threadIdx.x;
    const f32x4 a = ((const f32x4*)filt)[idx];
    const bf16x4 u = ((const bf16x4*)ugb)[idx];
    const bf16x4 t = ((const bf16x4*)htb)[idx];
    f32x4 hn;
#pragma unroll
    for (int e = 0; e < 4; ++e)
        hn[e] = fmaf((float)u[e], (float)t[e], -a[e]);
    ((f32x4*)out_upd)[(size_t)(NSTEP - 1) * S4 + idx] = hn;
    bf16x4 hb = {(bf16)hn[0], (bf16)hn[1], (bf16)hn[2], (bf16)hn[3]};
    ((bf16x4*)hnb)[idx] = hb;
}

// ---------------------------------------------------------------------------
// K5: output GEMM (N=512, K=512), XCD-swizzled: out = HNb @ Wo + bo (f32)
__global__ __launch_bounds__(256)
void gemm_out(const bf16* __restrict__ HNb,
              const bf16* __restrict__ Wo_t,
              const float* __restrict__ bo,
              float* __restrict__ outp) {
    __shared__ bf16 As[128 * 64];
    __shared__ bf16 Bs[64 * 64];

    const int bid = blockIdx.x;
    const int tid = threadIdx.x;

    const int k8  = bid & 7;
    const int s   = bid >> 3;
    const int colb = s >> 2;           // 0..7
    const int rowb = (k8 << 2) + (s & 3);
    const int brow = rowb * 128;
    const int bcol = colb * 64;

    const int wid  = tid >> 6;
    const int lane = tid & 63;
    const int wr = wid >> 1, wc = wid & 1;

    const int s_row  = tid >> 3;
    const int s_chnk = tid & 7;

    f32x4 acc[4][2] = {};

    for (int t = 0; t < 8; ++t) {
        const int k0 = t * 64;

#pragma unroll
        for (int c = 0; c < 4; ++c) {
            const int row = c * 32 + s_row;
            const int sc  = s_chnk ^ (row & 7);
            gload_lds16(HNb + (size_t)(brow + row) * 512 + k0 + sc * 8,
                        As + (size_t)(c * 256 + (wid << 6)) * 8);
        }
#pragma unroll
        for (int c = 0; c < 2; ++c) {
            const int row = c * 32 + s_row;
            const int sc  = s_chnk ^ (row & 7);
            gload_lds16(Wo_t + (size_t)(bcol + row) * 512 + k0 + sc * 8,
                        Bs + (size_t)(c * 256 + (wid << 6)) * 8);
        }
        __syncthreads();

#pragma unroll
        for (int ks = 0; ks < 2; ++ks) {
            const int kb = ks * 64 + ((lane >> 4) << 4);
            bf16x8 bfrag[2];
#pragma unroll
            for (int ni = 0; ni < 2; ++ni) {
                const int n = wc * 32 + ni * 16 + (lane & 15);
                bfrag[ni] = *(const bf16x8*)((const char*)Bs +
                                             n * 128 + (kb ^ ((n & 7) << 4)));
            }
#pragma unroll
            for (int mi = 0; mi < 4; ++mi) {
                const int m = wr * 64 + mi * 16 + (lane & 15);
                const bf16x8 afrag = *(const bf16x8*)((const char*)As +
                                                      m * 128 + (kb ^ ((m & 7) << 4)));
#pragma unroll
                for (int ni = 0; ni < 2; ++ni)
                    acc[mi][ni] = __builtin_amdgcn_mfma_f32_16x16x32_bf16(
                        afrag, bfrag[ni], acc[mi][ni], 0, 0, 0);
            }
        }
        __syncthreads();
    }

    const int lr4 = (lane >> 4) * 4;
    const int lc  = lane & 15;
#pragma unroll
    for (int mi = 0; mi < 4; ++mi) {
#pragma unroll
        for (int ni = 0; ni < 2; ++ni) {
            const int col = bcol + wc * 32 + ni * 16 + lc;
            const f32x4 a = acc[mi][ni];
#pragma unroll
            for (int r = 0; r < 4; ++r) {
                const int row = brow + wr * 64 + mi * 16 + lr4 + r;
                outp[(size_t)row * 512 + col] = a[r] + bo[col];
            }
        }
    }
}

// ---------------------------------------------------------------------------
extern "C" void kernel_launch(void* const* d_in, const int* in_sizes, int n_in,
                              void* d_out, int out_size, void* d_ws, size_t ws_size,
                              hipStream_t stream) {
    const float* sample   = (const float*)d_in[0];
    const float* hiddens  = (const float*)d_in[1];
    const float* mem_para = (const float*)d_in[2];
    const float* Wu = (const float*)d_in[3];
    const float* bu = (const float*)d_in[4];
    const float* Wr = (const float*)d_in[5];
    const float* br = (const float*)d_in[6];
    const float* Wm = (const float*)d_in[7];
    const float* bm = (const float*)d_in[8];
    const float* Wh = (const float*)d_in[9];
    const float* bh = (const float*)d_in[10];
    const float* Wo = (const float*)d_in[11];
    const float* bo = (const float*)d_in[12];

    float* out        = (float*)d_out;
    float* out_output = out;                                  // [B,512]
    float* out_upd    = out + SLICE;                          // [16,B,512]
    float* out_mg     = out + SLICE + (size_t)NSTEP * SLICE;  // [B,512]

    const float* hidden = hiddens + (size_t)(NSTEP - 1) * SLICE;

    // workspace layout; 4MB-aligned chunks
    char* ws = (char*)d_ws;
    bf16* Sb    = (bf16*)(ws);                          // sample bf16
    bf16* Hb    = (bf16*)(ws + (((size_t) 4) << 20));   // hidden bf16
    bf16* Mb    = (bf16*)(ws + (((size_t) 8) << 20));   // mem_para bf16
    bf16* RHb   = (bf16*)(ws + (((size_t)12) << 20));   // reset_gate*hidden
    bf16* HNb   = (bf16*)(ws + (((size_t)16) << 20));   // hidden_now
    bf16* UGb   = (bf16*)(ws + (((size_t)20) << 20));   // update_gate
    bf16* HTb   = (bf16*)(ws + (((size_t)24) << 20));   // h_tilde
    bf16* Wall_t = (bf16*)(ws + (((size_t)28) << 20));  // [1536][1536] (4.5MB)
    bf16* Wh_t  = (bf16*)(ws + (((size_t)33) << 20));   // [512][1024]
    bf16* Wo_t  = (bf16*)(ws + (((size_t)35) << 20));   // [512][512]
    float* filt = (float*)(ws + (((size_t)40) << 20));  // [B,512] f32 (8MB)

    dim3 blk(256);

    // 1. fused prep: converts + all weight transposes
    prep_all<<<8704, blk, 0, stream>>>(sample, hidden, mem_para,
                                       Wu, Wr, Wm, Wh, Wo,
                                       Sb, Hb, Mb, Wall_t, Wh_t, Wo_t);
    // 2. URM GEMM, XCD-swizzled (768 blocks)
    gemm_urm<<<768, blk, 0, stream>>>(
        Sb, Hb, Mb, Wall_t, bu, br, bm, UGb, RHb, out_mg);
    // 3. Wh GEMM (256, swizzled) + filter copy/sum stream (2048)
    gemm_wh_filter<<<256 + 2048, blk, 0, stream>>>(
        Sb, RHb, Wh_t, bh, HTb, hiddens, out_mg, out_upd, filt);
    // 4. combine -> out_upd[15] + HNb
    combine<<<S4 / 256, blk, 0, stream>>>(filt, UGb, HTb, out_upd, HNb);
    // 5. output GEMM, XCD-swizzled
    gemm_out<<<256, blk, 0, stream>>>(HNb, Wo_t, bo, out_output);
}